// Round 4
// baseline (88.545 us; speedup 1.0000x reference)
//
#include <hip/hip_runtime.h>

#define B 16
#define C 64
#define SS 4096      // H*W
#define TT 1024      // pooled keys
#define CQ 8         // C/8
#define CG 32        // C/2

typedef _Float16 h4 __attribute__((ext_vector_type(4)));
typedef float f32x16 __attribute__((ext_vector_type(16)));

#if __has_builtin(__builtin_amdgcn_exp2f)
#define EXP2(x) __builtin_amdgcn_exp2f(x)
#else
#define EXP2(x) exp2f(x)
#endif

#define MFMA328(a, b, c) __builtin_amdgcn_mfma_f32_32x32x8f16((a), (b), (c), 0, 0, 0)

// ---------------------------------------------------------------------------
// KP: one pass over x. Computes:
//   theta_t[b][s][o]  f16, scaled by log2(e)          (o-contiguous, 16B rows)
//   phi_t[b][t][o]    f16                              (o-contiguous)
//   g_blk[b][t>>2][c][t&3] f16  (blocked so KA staging reads are contiguous)
// Lane mapping: 4 consecutive threads = one 2x2 pool quad (t), pos = gid&3.
// 64-thread blocks: 1024 one-wave blocks -> ~16 waves/CU for latency hiding.
// ---------------------------------------------------------------------------
__global__ __launch_bounds__(64, 4) void k_proj(
        const float* __restrict__ x, const float* __restrict__ w_theta,
        const float* __restrict__ w_phi, const float* __restrict__ w_g,
        _Float16* __restrict__ theta_t, _Float16* __restrict__ phi_t,
        _Float16* __restrict__ g_blk) {
    int tid = threadIdx.x;
    int gid = blockIdx.x * 64 + tid;         // over B*SS
    int b = gid >> 12;
    int q = (gid >> 2) & 1023;               // t index (pool quad)
    int pos = gid & 3;
    int ph = q >> 5, pw = q & 31;
    int s = (2 * ph + (pos >> 1)) * 64 + 2 * pw + (pos & 1);
    const float* xb = x + ((size_t)b << 18) + s;

    float th[CQ], fp[CQ], fg[CG];
#pragma unroll
    for (int o = 0; o < CQ; ++o) { th[o] = 0.f; fp[o] = 0.f; }
#pragma unroll
    for (int o = 0; o < CG; ++o) fg[o] = 0.f;

#pragma unroll 8
    for (int c = 0; c < C; ++c) {
        float xv = xb[(size_t)c << 12];
#pragma unroll
        for (int o = 0; o < CQ; ++o) th[o] += w_theta[o * C + c] * xv;
#pragma unroll
        for (int o = 0; o < CQ; ++o) fp[o] += w_phi[o * C + c] * xv;
#pragma unroll
        for (int o = 0; o < CG; ++o) fg[o] += w_g[o * C + c] * xv;
    }

    const float LOG2E = 1.44269504088896f;
    union { _Float16 h[8]; float4 f4; } u;
#pragma unroll
    for (int o = 0; o < CQ; ++o) u.h[o] = (_Float16)(th[o] * LOG2E);
    *(float4*)&theta_t[(size_t)((b << 12) + s) * 8] = u.f4;

    // 2x2 max-pool across the quad's 4 lanes
#pragma unroll
    for (int o = 0; o < CQ; ++o) {
        fp[o] = fmaxf(fp[o], __shfl_xor(fp[o], 1));
        fp[o] = fmaxf(fp[o], __shfl_xor(fp[o], 2));
    }
#pragma unroll
    for (int o = 0; o < CG; ++o) {
        fg[o] = fmaxf(fg[o], __shfl_xor(fg[o], 1));
        fg[o] = fmaxf(fg[o], __shfl_xor(fg[o], 2));
    }
    if (pos == 0) {
        union { _Float16 h[8]; float4 f4; } v;
#pragma unroll
        for (int o = 0; o < CQ; ++o) v.h[o] = (_Float16)fp[o];
        *(float4*)&phi_t[(size_t)((b << 10) + q) * 8] = v.f4;
        _Float16* gb = g_blk + (size_t)(b * 256 + (q >> 2)) * 128 + (q & 3);
#pragma unroll
        for (int c2 = 0; c2 < CG; ++c2) gb[c2 * 4] = (_Float16)fg[c2];
    }
}

// ---------------------------------------------------------------------------
// KA: flash attention, swapped-operand 32x32x8 MFMA, P entirely in registers.
// Block = (b, 128 query rows), 4 waves x 32 rows. g for the whole batch is
// staged once in LDS (64 KB, XOR-swizzled 8B blocks); zero barriers in loop.
// ---------------------------------------------------------------------------
__global__ __launch_bounds__(256) void k_attn(
        const float* __restrict__ x, const _Float16* __restrict__ theta_t,
        const _Float16* __restrict__ phi_t, const _Float16* __restrict__ g_blk,
        const float* __restrict__ w_o, const float* __restrict__ gamma_p,
        float* __restrict__ out) {
    __shared__ _Float16 g_sh[CG * TT];       // 64 KB

    int tid = threadIdx.x;
    int bid = blockIdx.x;
    int wg = (bid & 7) * 64 + (bid >> 3);    // XCD-contiguous batches (512%8==0)
    int b = wg >> 5;
    int s0 = (wg & 31) * 128;
    int l = tid & 63;
    int ln = l & 31, hi = l >> 5;
    int sw = s0 + (tid >> 6) * 32;

    // ---- stage g (whole batch): thread (c = tid&31, jg = tid>>5) ----
    {
        int cst = tid & 31, jg = tid >> 5;
        const _Float16* gsrc = g_blk + (size_t)b * (256 * 128) + (size_t)cst * 4;
        _Float16* grow = g_sh + cst * TT;
#pragma unroll 4
        for (int i = 0; i < 32; ++i) {
            int j = jg + 8 * i;
            int js = (j & ~15) | ((j ^ cst) & 15);
            *(h4*)&grow[js * 4] = *(const h4*)&gsrc[(size_t)j * 128];
        }
    }

    // theta B-fragment (col s = sw+ln, k = o = 4*hi+i), loop-invariant
    h4 bth = *(const h4*)&theta_t[(size_t)((b << 12) + sw + ln) * 8 + 4 * hi];

    // w_o A-fragments: ch = mt*32+ln, k = c = 8*kk + 4*hi + i
    h4 a3[2][4];
#pragma unroll
    for (int mt = 0; mt < 2; ++mt)
#pragma unroll
        for (int kk = 0; kk < 4; ++kk) {
            float4 wv = *(const float4*)&w_o[(mt * 32 + ln) * CG + 8 * kk + 4 * hi];
            a3[mt][kk][0] = (_Float16)wv.x;
            a3[mt][kk][1] = (_Float16)wv.y;
            a3[mt][kk][2] = (_Float16)wv.z;
            a3[mt][kk][3] = (_Float16)wv.w;
        }

    const _Float16* phib = phi_t + ((size_t)b << 10) * 8;
    h4 aphi = *(const h4*)&phib[(size_t)ln * 8 + 4 * hi];

    __syncthreads();

    f32x16 zero;
#pragma unroll
    for (int r = 0; r < 16; ++r) zero[r] = 0.f;
    f32x16 acc = zero;
    float m2 = -1e30f, lsum = 0.f;

    for (int tc = 0; tc < TT / 32; ++tc) {
        int tbase = tc * 32;
        h4 acur = aphi;
        if (tc < TT / 32 - 1)
            aphi = *(const h4*)&phib[(size_t)(tbase + 32 + ln) * 8 + 4 * hi];

        // scores D[t][s], t local 0..31, s = sw+ln (lane-fixed)
        f32x16 sc = MFMA328(acur, bth, zero);

        // chunk max for this lane's s (16 regs + partner lane^32)
        float x0 = fmaxf(sc[0], sc[1]),  x1 = fmaxf(sc[2], sc[3]);
        float x2 = fmaxf(sc[4], sc[5]),  x3 = fmaxf(sc[6], sc[7]);
        float x4 = fmaxf(sc[8], sc[9]),  x5 = fmaxf(sc[10], sc[11]);
        float x6 = fmaxf(sc[12], sc[13]), x7 = fmaxf(sc[14], sc[15]);
        x0 = fmaxf(x0, x1); x2 = fmaxf(x2, x3); x4 = fmaxf(x4, x5); x6 = fmaxf(x6, x7);
        x0 = fmaxf(x0, x2); x4 = fmaxf(x4, x6);
        float mx = fmaxf(x0, x4);
        mx = fmaxf(mx, __shfl_xor(mx, 32));
        float nm = fmaxf(m2, mx);
        if (__any(nm > m2)) {
            float scl = EXP2(m2 - nm);
            m2 = nm;
            lsum *= scl;
#pragma unroll
            for (int r = 0; r < 16; ++r) acc[r] *= scl;
        }
        float ps = 0.f;
#pragma unroll
        for (int r = 0; r < 16; ++r) {
            float p = EXP2(sc[r] - m2);
            sc[r] = p;
            ps += p;
        }
        ps += __shfl_xor(ps, 32);
        lsum += ps;

        // PV: acc[c][s] += g[c][t] * P[t][s]; P regs ARE the B-fragments
#pragma unroll
        for (int kk = 0; kk < 4; ++kk) {
            h4 bp;
            bp[0] = (_Float16)sc[4 * kk + 0];
            bp[1] = (_Float16)sc[4 * kk + 1];
            bp[2] = (_Float16)sc[4 * kk + 2];
            bp[3] = (_Float16)sc[4 * kk + 3];
            int t0 = tbase + 8 * kk + 4 * hi;
            int j = t0 >> 2;
            int js = (j & ~15) | ((j ^ ln) & 15);
            h4 ag = *(const h4*)&g_sh[ln * TT + js * 4];
            acc = MFMA328(ag, bp, acc);
        }
    }

    // ---- epilogue: out = gamma * (w_o . attn/l) + x, attn regs -> B-frags ----
    float linv = 1.f / lsum;
    h4 bat[4];
#pragma unroll
    for (int kk = 0; kk < 4; ++kk) {
        bat[kk][0] = (_Float16)(acc[4 * kk + 0] * linv);
        bat[kk][1] = (_Float16)(acc[4 * kk + 1] * linv);
        bat[kk][2] = (_Float16)(acc[4 * kk + 2] * linv);
        bat[kk][3] = (_Float16)(acc[4 * kk + 3] * linv);
    }
    float gm = gamma_p[0];
#pragma unroll
    for (int mt = 0; mt < 2; ++mt) {
        f32x16 d = MFMA328(a3[mt][0], bat[0], zero);
        d = MFMA328(a3[mt][1], bat[1], d);
        d = MFMA328(a3[mt][2], bat[2], d);
        d = MFMA328(a3[mt][3], bat[3], d);
#pragma unroll
        for (int r = 0; r < 16; ++r) {
            int ch = mt * 32 + (r & 3) + 8 * (r >> 2) + 4 * hi;
            size_t idx = (((size_t)(b * C + ch)) << 12) + sw + ln;
            out[idx] = gm * d[r] + x[idx];
        }
    }
}

// ---------------------------------------------------------------------------
extern "C" void kernel_launch(void* const* d_in, const int* in_sizes, int n_in,
                              void* d_out, int out_size, void* d_ws, size_t ws_size,
                              hipStream_t stream) {
    const float* x       = (const float*)d_in[0];
    const float* w_theta = (const float*)d_in[1];
    const float* w_phi   = (const float*)d_in[2];
    const float* w_g     = (const float*)d_in[3];
    const float* w_o     = (const float*)d_in[4];
    const float* gamma   = (const float*)d_in[5];
    float* out = (float*)d_out;

    _Float16* ws      = (_Float16*)d_ws;
    _Float16* theta_t = ws;                             // B*SS*8  halves
    _Float16* phi_t   = theta_t + (size_t)B * SS * 8;   // B*TT*8
    _Float16* g_blk   = phi_t + (size_t)B * TT * 8;     // B*TT*CG (blocked)

    k_proj<<<(B * SS) / 64, 64, 0, stream>>>(x, w_theta, w_phi, w_g,
                                             theta_t, phi_t, g_blk);
    k_attn<<<B * (SS / 128), 256, 0, stream>>>(x, theta_t, phi_t, g_blk,
                                               w_o, gamma, out);
}

// Round 5
// 69.549 us; speedup vs baseline: 1.2731x; 1.2731x over previous
//
#include <hip/hip_runtime.h>

#define B 16
#define C 64
#define SS 4096      // H*W
#define TT 1024      // pooled keys
#define CQ 8         // C/8
#define CG 32        // C/2

typedef _Float16 h4 __attribute__((ext_vector_type(4)));
typedef float f32x16 __attribute__((ext_vector_type(16)));

#if __has_builtin(__builtin_amdgcn_exp2f)
#define EXP2(x) __builtin_amdgcn_exp2f(x)
#else
#define EXP2(x) exp2f(x)
#endif

#define MFMA328(a, b, c) __builtin_amdgcn_mfma_f32_32x32x8f16((a), (b), (c), 0, 0, 0)

// async global->LDS, 16B per lane; lds base must be wave-uniform
__device__ __forceinline__ void async_ld16(void* lds, const void* g) {
    __builtin_amdgcn_global_load_lds(
        (const __attribute__((address_space(1))) unsigned int*)g,
        (__attribute__((address_space(3))) unsigned int*)lds,
        16, 0, 0);
}

// ---------------------------------------------------------------------------
// KP: one pass over x -> theta_t (f16, *log2e), phi_t, g_blk (maxpooled).
// Block = 256 threads = contiguous 256-pixel range of one batch. x streamed
// through LDS in 16-channel chunks via global_load_lds (double-buffered,
// 2-phase pipeline): DMA of chunk k+1 overlaps FMA on chunk k.
// Lane mapping: 4 consecutive threads = one 2x2 pool quad.
// ---------------------------------------------------------------------------
#define CHUNK 16
__global__ __launch_bounds__(256) void k_proj(
        const float* __restrict__ x, const float* __restrict__ w_theta,
        const float* __restrict__ w_phi, const float* __restrict__ w_g,
        _Float16* __restrict__ theta_t, _Float16* __restrict__ phi_t,
        _Float16* __restrict__ g_blk) {
    __shared__ float xb_s[2][CHUNK][256];    // 32 KB

    int tid = threadIdx.x;
    int wv = tid >> 6, lane = tid & 63;
    int b = blockIdx.x >> 4;
    int s_base = (blockIdx.x & 15) * 256;    // 4 pixel rows

    // quad mapping within block
    int pos = tid & 3;
    int ql = tid >> 2;                       // 0..63 local quads
    int ph_l = ql >> 5, pw_l = ql & 31;
    int dh = pos >> 1, dw = pos & 1;
    int s_local = 128 * ph_l + 64 * dh + 2 * pw_l + dw;

    const float* xg = x + ((size_t)b << 18) + s_base;

    float th[CQ], fp[CQ], fg[CG];
#pragma unroll
    for (int o = 0; o < CQ; ++o) { th[o] = 0.f; fp[o] = 0.f; }
#pragma unroll
    for (int o = 0; o < CG; ++o) fg[o] = 0.f;

    // prologue: stage chunk 0
#pragma unroll
    for (int i = 0; i < CHUNK / 4; ++i) {
        int r = (CHUNK / 4) * wv + i;
        async_ld16(&xb_s[0][r][0], xg + (size_t)r * SS + lane * 4);
    }
    __syncthreads();

    for (int k = 0; k < C / CHUNK; ++k) {
        if (k < C / CHUNK - 1) {
            int c0n = (k + 1) * CHUNK;
            int bn = (k + 1) & 1;
#pragma unroll
            for (int i = 0; i < CHUNK / 4; ++i) {
                int r = (CHUNK / 4) * wv + i;
                async_ld16(&xb_s[bn][r][0], xg + (size_t)(c0n + r) * SS + lane * 4);
            }
        }
        int bc = k & 1, c0 = k * CHUNK;
#pragma unroll
        for (int cc = 0; cc < CHUNK; ++cc) {
            float xv = xb_s[bc][cc][s_local];
            int c = c0 + cc;
#pragma unroll
            for (int o = 0; o < CQ; ++o) th[o] += w_theta[o * C + c] * xv;
#pragma unroll
            for (int o = 0; o < CQ; ++o) fp[o] += w_phi[o * C + c] * xv;
#pragma unroll
            for (int o = 0; o < CG; ++o) fg[o] += w_g[o * C + c] * xv;
        }
        __syncthreads();
    }

    int s_g = s_base + s_local;
    const float LOG2E = 1.44269504088896f;
    union { _Float16 h[8]; float4 f4; } u;
#pragma unroll
    for (int o = 0; o < CQ; ++o) u.h[o] = (_Float16)(th[o] * LOG2E);
    *(float4*)&theta_t[(size_t)((b << 12) + s_g) * 8] = u.f4;

    // 2x2 max-pool across the quad's 4 lanes
#pragma unroll
    for (int o = 0; o < CQ; ++o) {
        fp[o] = fmaxf(fp[o], __shfl_xor(fp[o], 1));
        fp[o] = fmaxf(fp[o], __shfl_xor(fp[o], 2));
    }
#pragma unroll
    for (int o = 0; o < CG; ++o) {
        fg[o] = fmaxf(fg[o], __shfl_xor(fg[o], 1));
        fg[o] = fmaxf(fg[o], __shfl_xor(fg[o], 2));
    }
    if (pos == 0) {
        int ph_g = 2 * (blockIdx.x & 15) + ph_l;
        int qg = ph_g * 32 + pw_l;
        union { _Float16 h[8]; float4 f4; } v;
#pragma unroll
        for (int o = 0; o < CQ; ++o) v.h[o] = (_Float16)fp[o];
        *(float4*)&phi_t[(size_t)((b << 10) + qg) * 8] = v.f4;
        _Float16* gb = g_blk + (size_t)(b * 256 + (qg >> 2)) * 128 + (qg & 3);
#pragma unroll
        for (int c2 = 0; c2 < CG; ++c2) gb[c2 * 4] = (_Float16)fg[c2];
    }
}

// ---------------------------------------------------------------------------
// KA: flash attention, swapped-operand 32x32x8 MFMA, P entirely in registers.
// Block = (b, 128 query rows), 4 waves x 32 rows. g for the whole batch is
// staged once in LDS (64 KB, XOR-swizzled 8B blocks); zero barriers in loop.
// ---------------------------------------------------------------------------
__global__ __launch_bounds__(256) void k_attn(
        const float* __restrict__ x, const _Float16* __restrict__ theta_t,
        const _Float16* __restrict__ phi_t, const _Float16* __restrict__ g_blk,
        const float* __restrict__ w_o, const float* __restrict__ gamma_p,
        float* __restrict__ out) {
    __shared__ _Float16 g_sh[CG * TT];       // 64 KB

    int tid = threadIdx.x;
    int bid = blockIdx.x;
    int wg = (bid & 7) * 64 + (bid >> 3);    // XCD-contiguous batches (512%8==0)
    int b = wg >> 5;
    int s0 = (wg & 31) * 128;
    int l = tid & 63;
    int ln = l & 31, hi = l >> 5;
    int sw = s0 + (tid >> 6) * 32;

    // ---- stage g (whole batch): thread (c = tid&31, jg = tid>>5) ----
    {
        int cst = tid & 31, jg = tid >> 5;
        const _Float16* gsrc = g_blk + (size_t)b * (256 * 128) + (size_t)cst * 4;
        _Float16* grow = g_sh + cst * TT;
#pragma unroll 4
        for (int i = 0; i < 32; ++i) {
            int j = jg + 8 * i;
            int js = (j & ~15) | ((j ^ cst) & 15);
            *(h4*)&grow[js * 4] = *(const h4*)&gsrc[(size_t)j * 128];
        }
    }

    // theta B-fragment (col s = sw+ln, k = o = 4*hi+i), loop-invariant
    h4 bth = *(const h4*)&theta_t[(size_t)((b << 12) + sw + ln) * 8 + 4 * hi];

    // w_o A-fragments: ch = mt*32+ln, k = c = 8*kk + 4*hi + i
    h4 a3[2][4];
#pragma unroll
    for (int mt = 0; mt < 2; ++mt)
#pragma unroll
        for (int kk = 0; kk < 4; ++kk) {
            float4 wv = *(const float4*)&w_o[(mt * 32 + ln) * CG + 8 * kk + 4 * hi];
            a3[mt][kk][0] = (_Float16)wv.x;
            a3[mt][kk][1] = (_Float16)wv.y;
            a3[mt][kk][2] = (_Float16)wv.z;
            a3[mt][kk][3] = (_Float16)wv.w;
        }

    const _Float16* phib = phi_t + ((size_t)b << 10) * 8;
    h4 aphi = *(const h4*)&phib[(size_t)ln * 8 + 4 * hi];

    __syncthreads();

    f32x16 zero;
#pragma unroll
    for (int r = 0; r < 16; ++r) zero[r] = 0.f;
    f32x16 acc = zero;
    float m2 = -1e30f, lsum = 0.f;

    for (int tc = 0; tc < TT / 32; ++tc) {
        int tbase = tc * 32;
        h4 acur = aphi;
        if (tc < TT / 32 - 1)
            aphi = *(const h4*)&phib[(size_t)(tbase + 32 + ln) * 8 + 4 * hi];

        // scores D[t][s], t local 0..31, s = sw+ln (lane-fixed)
        f32x16 sc = MFMA328(acur, bth, zero);

        // chunk max for this lane's s (16 regs + partner lane^32)
        float x0 = fmaxf(sc[0], sc[1]),  x1 = fmaxf(sc[2], sc[3]);
        float x2 = fmaxf(sc[4], sc[5]),  x3 = fmaxf(sc[6], sc[7]);
        float x4 = fmaxf(sc[8], sc[9]),  x5 = fmaxf(sc[10], sc[11]);
        float x6 = fmaxf(sc[12], sc[13]), x7 = fmaxf(sc[14], sc[15]);
        x0 = fmaxf(x0, x1); x2 = fmaxf(x2, x3); x4 = fmaxf(x4, x5); x6 = fmaxf(x6, x7);
        x0 = fmaxf(x0, x2); x4 = fmaxf(x4, x6);
        float mx = fmaxf(x0, x4);
        mx = fmaxf(mx, __shfl_xor(mx, 32));
        float nm = fmaxf(m2, mx);
        if (__any(nm > m2)) {
            float scl = EXP2(m2 - nm);
            m2 = nm;
            lsum *= scl;
#pragma unroll
            for (int r = 0; r < 16; ++r) acc[r] *= scl;
        }
        float ps = 0.f;
#pragma unroll
        for (int r = 0; r < 16; ++r) {
            float p = EXP2(sc[r] - m2);
            sc[r] = p;
            ps += p;
        }
        ps += __shfl_xor(ps, 32);
        lsum += ps;

        // PV: acc[c][s] += g[c][t] * P[t][s]; P regs ARE the B-fragments
#pragma unroll
        for (int kk = 0; kk < 4; ++kk) {
            h4 bp;
            bp[0] = (_Float16)sc[4 * kk + 0];
            bp[1] = (_Float16)sc[4 * kk + 1];
            bp[2] = (_Float16)sc[4 * kk + 2];
            bp[3] = (_Float16)sc[4 * kk + 3];
            int t0 = tbase + 8 * kk + 4 * hi;
            int j = t0 >> 2;
            int js = (j & ~15) | ((j ^ ln) & 15);
            h4 ag = *(const h4*)&g_sh[ln * TT + js * 4];
            acc = MFMA328(ag, bp, acc);
        }
    }

    // ---- epilogue: out = gamma * (w_o . attn/l) + x, attn regs -> B-frags ----
    float linv = 1.f / lsum;
    h4 bat[4];
#pragma unroll
    for (int kk = 0; kk < 4; ++kk) {
        bat[kk][0] = (_Float16)(acc[4 * kk + 0] * linv);
        bat[kk][1] = (_Float16)(acc[4 * kk + 1] * linv);
        bat[kk][2] = (_Float16)(acc[4 * kk + 2] * linv);
        bat[kk][3] = (_Float16)(acc[4 * kk + 3] * linv);
    }
    float gm = gamma_p[0];
#pragma unroll
    for (int mt = 0; mt < 2; ++mt) {
        f32x16 d = MFMA328(a3[mt][0], bat[0], zero);
        d = MFMA328(a3[mt][1], bat[1], d);
        d = MFMA328(a3[mt][2], bat[2], d);
        d = MFMA328(a3[mt][3], bat[3], d);
#pragma unroll
        for (int r = 0; r < 16; ++r) {
            int ch = mt * 32 + (r & 3) + 8 * (r >> 2) + 4 * hi;
            size_t idx = (((size_t)(b * C + ch)) << 12) + sw + ln;
            out[idx] = gm * d[r] + x[idx];
        }
    }
}

// ---------------------------------------------------------------------------
extern "C" void kernel_launch(void* const* d_in, const int* in_sizes, int n_in,
                              void* d_out, int out_size, void* d_ws, size_t ws_size,
                              hipStream_t stream) {
    const float* x       = (const float*)d_in[0];
    const float* w_theta = (const float*)d_in[1];
    const float* w_phi   = (const float*)d_in[2];
    const float* w_g     = (const float*)d_in[3];
    const float* w_o     = (const float*)d_in[4];
    const float* gamma   = (const float*)d_in[5];
    float* out = (float*)d_out;

    _Float16* ws      = (_Float16*)d_ws;
    _Float16* theta_t = ws;                             // B*SS*8  halves
    _Float16* phi_t   = theta_t + (size_t)B * SS * 8;   // B*TT*8
    _Float16* g_blk   = phi_t + (size_t)B * TT * 8;     // B*TT*CG (blocked)

    k_proj<<<(B * SS) / 256, 256, 0, stream>>>(x, w_theta, w_phi, w_g,
                                               theta_t, phi_t, g_blk);
    k_attn<<<B * (SS / 128), 256, 0, stream>>>(x, theta_t, phi_t, g_blk,
                                               w_o, gamma, out);
}

// Round 6
// 46.089 us; speedup vs baseline: 1.9212x; 1.5090x over previous
//
#include <hip/hip_runtime.h>

#define B 16
#define C 64
#define SS 4096      // H*W
#define TT 1024      // pooled keys
#define CQ 8         // C/8
#define CG 32        // C/2

typedef _Float16 h4 __attribute__((ext_vector_type(4)));
typedef float f32x16 __attribute__((ext_vector_type(16)));

#if __has_builtin(__builtin_amdgcn_exp2f)
#define EXP2(x) __builtin_amdgcn_exp2f(x)
#else
#define EXP2(x) exp2f(x)
#endif

#define MFMA328(a, b, c) __builtin_amdgcn_mfma_f32_32x32x8f16((a), (b), (c), 0, 0, 0)

// ---------------------------------------------------------------------------
// KP: projections via MFMA, zero LDS, zero barriers. Each wave:
//   - holds W = [w_theta*log2e(8); w_phi(8); w_g(16)] + [w_g(16); pad(16)]
//     as A-fragments in registers (loaded once),
//   - computes D[o][s] for 64 pixels = two 32-px segments of image rows
//     (h, h+1) -> 2x2 maxpool = reg-max of the two row tiles + shfl_xor(1),
//   - 64 independent coalesced f32 loads/lane, all in flight at once.
// Outputs: theta_t[b][s][o] f16 (o-contig, pre-scaled log2e), phi_t[b][t][o],
//          g_out[b][c][t].
// ---------------------------------------------------------------------------
__global__ __launch_bounds__(256) void k_proj(
        const float* __restrict__ x, const float* __restrict__ w_theta,
        const float* __restrict__ w_phi, const float* __restrict__ w_g,
        _Float16* __restrict__ theta_t, _Float16* __restrict__ phi_t,
        _Float16* __restrict__ g_out) {
    int tid = threadIdx.x;
    int W = blockIdx.x * 4 + (tid >> 6);     // 1024 wave-tasks
    int l = tid & 63;
    int ln = l & 31, hi = l >> 5;
    int b = W >> 6, ws = W & 63;
    int rp = ws >> 1, wt = ws & 1;           // row-pair 0..31, w-tile 0..1
    int sA = rp * 128 + wt * 32 + ln;        // pixel (2rp, 32wt+ln)

    // ---- A-fragments (weights), loaded once ----
    const float LOG2E = 1.44269504088896f;
    float wsc = 1.f;
    const float* wr0;
    if (ln < 8)       { wr0 = w_theta + ln * C; wsc = LOG2E; }
    else if (ln < 16) { wr0 = w_phi + (ln - 8) * C; }
    else              { wr0 = w_g + (ln - 16) * C; }
    const float* wr1 = w_g + (16 + (ln & 15)) * C;  // used only when ln<16
    bool t1v = ln < 16;

    h4 wa0[8], wa1[8];
#pragma unroll
    for (int kk = 0; kk < 8; ++kk) {
        float4 v0 = *(const float4*)&wr0[8 * kk + 4 * hi];
        float4 v1 = *(const float4*)&wr1[8 * kk + 4 * hi];
        wa0[kk][0] = (_Float16)(v0.x * wsc);
        wa0[kk][1] = (_Float16)(v0.y * wsc);
        wa0[kk][2] = (_Float16)(v0.z * wsc);
        wa0[kk][3] = (_Float16)(v0.w * wsc);
        wa1[kk][0] = t1v ? (_Float16)v1.x : (_Float16)0.f;
        wa1[kk][1] = t1v ? (_Float16)v1.y : (_Float16)0.f;
        wa1[kk][2] = t1v ? (_Float16)v1.z : (_Float16)0.f;
        wa1[kk][3] = t1v ? (_Float16)v1.w : (_Float16)0.f;
    }

    // ---- x loads: 64 independent coalesced scalar f32 per lane ----
    const float* xb = x + ((size_t)b << 18);
    float xA[8][4], xB[8][4];
#pragma unroll
    for (int kk = 0; kk < 8; ++kk)
#pragma unroll
        for (int i = 0; i < 4; ++i) {
            int c = 8 * kk + 4 * hi + i;
            xA[kk][i] = xb[((size_t)c << 12) + sA];
            xB[kk][i] = xb[((size_t)c << 12) + sA + 64];
        }

    f32x16 aA0, aA1, aB0, aB1;
#pragma unroll
    for (int r = 0; r < 16; ++r) { aA0[r] = 0.f; aA1[r] = 0.f; aB0[r] = 0.f; aB1[r] = 0.f; }

#pragma unroll
    for (int kk = 0; kk < 8; ++kk) {
        h4 bA, bB;
#pragma unroll
        for (int i = 0; i < 4; ++i) {
            bA[i] = (_Float16)xA[kk][i];
            bB[i] = (_Float16)xB[kk][i];
        }
        aA0 = MFMA328(wa0[kk], bA, aA0);
        aB0 = MFMA328(wa0[kk], bB, aB0);
        aA1 = MFMA328(wa1[kk], bA, aA1);
        aB1 = MFMA328(wa1[kk], bB, aB1);
    }

    // ---- theta (rows 0-7 = regs 0-3 + 4hi), no pooling ----
    {
        h4 tv;
#pragma unroll
        for (int r = 0; r < 4; ++r) tv[r] = (_Float16)aA0[r];
        *(h4*)&theta_t[(size_t)((b << 12) + sA) * 8 + 4 * hi] = tv;
#pragma unroll
        for (int r = 0; r < 4; ++r) tv[r] = (_Float16)aB0[r];
        *(h4*)&theta_t[(size_t)((b << 12) + sA + 64) * 8 + 4 * hi] = tv;
    }

    // ---- pooled phi / g ----
    int t = rp * 32 + wt * 16 + (ln >> 1);
    float pv[4];
#pragma unroll
    for (int j = 0; j < 4; ++j) {
        float m = fmaxf(aA0[4 + j], aB0[4 + j]);
        m = fmaxf(m, __shfl_xor(m, 1));
        pv[j] = m;
    }
    float gv[4][4];
#pragma unroll
    for (int j = 0; j < 4; ++j) {
        float m0 = fmaxf(aA0[8 + j],  aB0[8 + j]);
        float m1 = fmaxf(aA0[12 + j], aB0[12 + j]);
        float m2 = fmaxf(aA1[j],      aB1[j]);
        float m3 = fmaxf(aA1[4 + j],  aB1[4 + j]);
        gv[0][j] = fmaxf(m0, __shfl_xor(m0, 1));
        gv[1][j] = fmaxf(m1, __shfl_xor(m1, 1));
        gv[2][j] = fmaxf(m2, __shfl_xor(m2, 1));
        gv[3][j] = fmaxf(m3, __shfl_xor(m3, 1));
    }
    if ((l & 1) == 0) {
        h4 pj;
#pragma unroll
        for (int j = 0; j < 4; ++j) pj[j] = (_Float16)pv[j];
        *(h4*)&phi_t[(size_t)((b << 10) + t) * 8 + 4 * hi] = pj;
#pragma unroll
        for (int part = 0; part < 4; ++part) {
            int cbase = part * 8 + 4 * hi;
#pragma unroll
            for (int j = 0; j < 4; ++j)
                g_out[((size_t)(b * CG + cbase + j) << 10) + t] = (_Float16)gv[part][j];
        }
    }
}

// ---------------------------------------------------------------------------
// KA: flash attention, swapped-operand 32x32x8 MFMA, P entirely in registers.
// Block = (b, 128 query rows), 4 waves x 32 rows. g for the whole batch is
// staged once in LDS (64 KB, XOR-swizzled 8B blocks); zero barriers in loop.
// ---------------------------------------------------------------------------
__global__ __launch_bounds__(256) void k_attn(
        const float* __restrict__ x, const _Float16* __restrict__ theta_t,
        const _Float16* __restrict__ phi_t, const _Float16* __restrict__ g_in,
        const float* __restrict__ w_o, const float* __restrict__ gamma_p,
        float* __restrict__ out) {
    __shared__ _Float16 g_sh[CG * TT];       // 64 KB

    int tid = threadIdx.x;
    int bid = blockIdx.x;
    int wg = (bid & 7) * 64 + (bid >> 3);    // XCD-contiguous batches (512%8==0)
    int b = wg >> 5;
    int s0 = (wg & 31) * 128;
    int l = tid & 63;
    int ln = l & 31, hi = l >> 5;
    int sw = s0 + (tid >> 6) * 32;

    // ---- stage g (whole batch): thread (c = tid&31, jg = tid>>5) ----
    {
        int cst = tid & 31, jg = tid >> 5;
        const _Float16* gsrc = g_in + (size_t)(b * CG + cst) * TT;
        _Float16* grow = g_sh + cst * TT;
#pragma unroll 4
        for (int i = 0; i < 32; ++i) {
            int j = jg + 8 * i;
            int js = (j & ~15) | ((j ^ cst) & 15);
            *(h4*)&grow[js * 4] = *(const h4*)&gsrc[(size_t)j * 4];
        }
    }

    // theta B-fragment (col s = sw+ln, k = o = 4*hi+i), loop-invariant
    h4 bth = *(const h4*)&theta_t[(size_t)((b << 12) + sw + ln) * 8 + 4 * hi];

    // w_o A-fragments: ch = mt*32+ln, k = c = 8*kk + 4*hi + i
    h4 a3[2][4];
#pragma unroll
    for (int mt = 0; mt < 2; ++mt)
#pragma unroll
        for (int kk = 0; kk < 4; ++kk) {
            float4 wv = *(const float4*)&w_o[(mt * 32 + ln) * CG + 8 * kk + 4 * hi];
            a3[mt][kk][0] = (_Float16)wv.x;
            a3[mt][kk][1] = (_Float16)wv.y;
            a3[mt][kk][2] = (_Float16)wv.z;
            a3[mt][kk][3] = (_Float16)wv.w;
        }

    const _Float16* phib = phi_t + ((size_t)b << 10) * 8;
    h4 aphi = *(const h4*)&phib[(size_t)ln * 8 + 4 * hi];

    __syncthreads();

    f32x16 zero;
#pragma unroll
    for (int r = 0; r < 16; ++r) zero[r] = 0.f;
    f32x16 acc = zero;
    float m2 = -1e30f, lsum = 0.f;

    for (int tc = 0; tc < TT / 32; ++tc) {
        int tbase = tc * 32;
        h4 acur = aphi;
        if (tc < TT / 32 - 1)
            aphi = *(const h4*)&phib[(size_t)(tbase + 32 + ln) * 8 + 4 * hi];

        // scores D[t][s], t local 0..31, s = sw+ln (lane-fixed)
        f32x16 sc = MFMA328(acur, bth, zero);

        // chunk max for this lane's s (16 regs + partner lane^32)
        float x0 = fmaxf(sc[0], sc[1]),  x1 = fmaxf(sc[2], sc[3]);
        float x2 = fmaxf(sc[4], sc[5]),  x3 = fmaxf(sc[6], sc[7]);
        float x4 = fmaxf(sc[8], sc[9]),  x5 = fmaxf(sc[10], sc[11]);
        float x6 = fmaxf(sc[12], sc[13]), x7 = fmaxf(sc[14], sc[15]);
        x0 = fmaxf(x0, x1); x2 = fmaxf(x2, x3); x4 = fmaxf(x4, x5); x6 = fmaxf(x6, x7);
        x0 = fmaxf(x0, x2); x4 = fmaxf(x4, x6);
        float mx = fmaxf(x0, x4);
        mx = fmaxf(mx, __shfl_xor(mx, 32));
        float nm = fmaxf(m2, mx);
        if (__any(nm > m2)) {
            float scl = EXP2(m2 - nm);
            m2 = nm;
            lsum *= scl;
#pragma unroll
            for (int r = 0; r < 16; ++r) acc[r] *= scl;
        }
        float ps = 0.f;
#pragma unroll
        for (int r = 0; r < 16; ++r) {
            float p = EXP2(sc[r] - m2);
            sc[r] = p;
            ps += p;
        }
        ps += __shfl_xor(ps, 32);
        lsum += ps;

        // PV: acc[c][s] += g[c][t] * P[t][s]; P regs ARE the B-fragments
#pragma unroll
        for (int kk = 0; kk < 4; ++kk) {
            h4 bp;
            bp[0] = (_Float16)sc[4 * kk + 0];
            bp[1] = (_Float16)sc[4 * kk + 1];
            bp[2] = (_Float16)sc[4 * kk + 2];
            bp[3] = (_Float16)sc[4 * kk + 3];
            int t0 = tbase + 8 * kk + 4 * hi;
            int j = t0 >> 2;
            int js = (j & ~15) | ((j ^ ln) & 15);
            h4 ag = *(const h4*)&g_sh[ln * TT + js * 4];
            acc = MFMA328(ag, bp, acc);
        }
    }

    // ---- epilogue: out = gamma * (w_o . attn/l) + x, attn regs -> B-frags ----
    float linv = 1.f / lsum;
    h4 bat[4];
#pragma unroll
    for (int kk = 0; kk < 4; ++kk) {
        bat[kk][0] = (_Float16)(acc[4 * kk + 0] * linv);
        bat[kk][1] = (_Float16)(acc[4 * kk + 1] * linv);
        bat[kk][2] = (_Float16)(acc[4 * kk + 2] * linv);
        bat[kk][3] = (_Float16)(acc[4 * kk + 3] * linv);
    }
    float gm = gamma_p[0];
#pragma unroll
    for (int mt = 0; mt < 2; ++mt) {
        f32x16 d = MFMA328(a3[mt][0], bat[0], zero);
        d = MFMA328(a3[mt][1], bat[1], d);
        d = MFMA328(a3[mt][2], bat[2], d);
        d = MFMA328(a3[mt][3], bat[3], d);
#pragma unroll
        for (int r = 0; r < 16; ++r) {
            int ch = mt * 32 + (r & 3) + 8 * (r >> 2) + 4 * hi;
            size_t idx = (((size_t)(b * C + ch)) << 12) + sw + ln;
            out[idx] = gm * d[r] + x[idx];
        }
    }
}

// ---------------------------------------------------------------------------
extern "C" void kernel_launch(void* const* d_in, const int* in_sizes, int n_in,
                              void* d_out, int out_size, void* d_ws, size_t ws_size,
                              hipStream_t stream) {
    const float* x       = (const float*)d_in[0];
    const float* w_theta = (const float*)d_in[1];
    const float* w_phi   = (const float*)d_in[2];
    const float* w_g     = (const float*)d_in[3];
    const float* w_o     = (const float*)d_in[4];
    const float* gamma   = (const float*)d_in[5];
    float* out = (float*)d_out;

    _Float16* ws      = (_Float16*)d_ws;
    _Float16* theta_t = ws;                             // B*SS*8  halves
    _Float16* phi_t   = theta_t + (size_t)B * SS * 8;   // B*TT*8
    _Float16* g_h     = phi_t + (size_t)B * TT * 8;     // B*CG*TT (plain [c][t])

    k_proj<<<256, 256, 0, stream>>>(x, w_theta, w_phi, w_g, theta_t, phi_t, g_h);
    k_attn<<<B * (SS / 128), 256, 0, stream>>>(x, theta_t, phi_t, g_h,
                                               w_o, gamma, out);
}

// Round 8
// 44.413 us; speedup vs baseline: 1.9937x; 1.0377x over previous
//
#include <hip/hip_runtime.h>

#define B 16
#define C 64
#define SS 4096      // H*W
#define TT 1024      // pooled keys
#define CQ 8         // C/8
#define CG 32        // C/2

typedef _Float16 h4 __attribute__((ext_vector_type(4)));
typedef float f32x16 __attribute__((ext_vector_type(16)));

#if __has_builtin(__builtin_amdgcn_exp2f)
#define EXP2(x) __builtin_amdgcn_exp2f(x)
#else
#define EXP2(x) exp2f(x)
#endif

#define MFMA328(a, b, c) __builtin_amdgcn_mfma_f32_32x32x8f16((a), (b), (c), 0, 0, 0)

// ---------------------------------------------------------------------------
// KP: projections via MFMA, zero LDS, zero barriers. Each wave:
//   - holds W = [w_theta*log2e(8); w_phi(8); w_g(16)] + [w_g(16); pad(16)]
//     as A-fragments in registers (loaded once),
//   - computes D[o][s] for 64 pixels = two 32-px segments of image rows
//     (h, h+1) -> 2x2 maxpool = reg-max of the two row tiles + shfl_xor(1),
//   - 64 independent coalesced f32 loads/lane, all in flight at once.
// Outputs: theta_t[b][s][o] f16 (o-contig, pre-scaled log2e), phi_t[b][t][o],
//          g_blk[b][t>>2][c][t&3] f16 (blocked: KA frag loads are 512B-coalesced)
// ---------------------------------------------------------------------------
__global__ __launch_bounds__(256) void k_proj(
        const float* __restrict__ x, const float* __restrict__ w_theta,
        const float* __restrict__ w_phi, const float* __restrict__ w_g,
        _Float16* __restrict__ theta_t, _Float16* __restrict__ phi_t,
        _Float16* __restrict__ g_blk) {
    int tid = threadIdx.x;
    int W = blockIdx.x * 4 + (tid >> 6);     // 1024 wave-tasks
    int l = tid & 63;
    int ln = l & 31, hi = l >> 5;
    int b = W >> 6, ws = W & 63;
    int rp = ws >> 1, wt = ws & 1;           // row-pair 0..31, w-tile 0..1
    int sA = rp * 128 + wt * 32 + ln;        // pixel (2rp, 32wt+ln)

    // ---- A-fragments (weights), loaded once ----
    const float LOG2E = 1.44269504088896f;
    float wsc = 1.f;
    const float* wr0;
    if (ln < 8)       { wr0 = w_theta + ln * C; wsc = LOG2E; }
    else if (ln < 16) { wr0 = w_phi + (ln - 8) * C; }
    else              { wr0 = w_g + (ln - 16) * C; }
    const float* wr1 = w_g + (16 + (ln & 15)) * C;  // used only when ln<16
    bool t1v = ln < 16;

    h4 wa0[8], wa1[8];
#pragma unroll
    for (int kk = 0; kk < 8; ++kk) {
        float4 v0 = *(const float4*)&wr0[8 * kk + 4 * hi];
        float4 v1 = *(const float4*)&wr1[8 * kk + 4 * hi];
        wa0[kk][0] = (_Float16)(v0.x * wsc);
        wa0[kk][1] = (_Float16)(v0.y * wsc);
        wa0[kk][2] = (_Float16)(v0.z * wsc);
        wa0[kk][3] = (_Float16)(v0.w * wsc);
        wa1[kk][0] = t1v ? (_Float16)v1.x : (_Float16)0.f;
        wa1[kk][1] = t1v ? (_Float16)v1.y : (_Float16)0.f;
        wa1[kk][2] = t1v ? (_Float16)v1.z : (_Float16)0.f;
        wa1[kk][3] = t1v ? (_Float16)v1.w : (_Float16)0.f;
    }

    // ---- x loads: 64 independent coalesced scalar f32 per lane ----
    const float* xb = x + ((size_t)b << 18);
    float xA[8][4], xB[8][4];
#pragma unroll
    for (int kk = 0; kk < 8; ++kk)
#pragma unroll
        for (int i = 0; i < 4; ++i) {
            int c = 8 * kk + 4 * hi + i;
            xA[kk][i] = xb[((size_t)c << 12) + sA];
            xB[kk][i] = xb[((size_t)c << 12) + sA + 64];
        }

    f32x16 aA0, aA1, aB0, aB1;
#pragma unroll
    for (int r = 0; r < 16; ++r) { aA0[r] = 0.f; aA1[r] = 0.f; aB0[r] = 0.f; aB1[r] = 0.f; }

#pragma unroll
    for (int kk = 0; kk < 8; ++kk) {
        h4 bA, bB;
#pragma unroll
        for (int i = 0; i < 4; ++i) {
            bA[i] = (_Float16)xA[kk][i];
            bB[i] = (_Float16)xB[kk][i];
        }
        aA0 = MFMA328(wa0[kk], bA, aA0);
        aB0 = MFMA328(wa0[kk], bB, aB0);
        aA1 = MFMA328(wa1[kk], bA, aA1);
        aB1 = MFMA328(wa1[kk], bB, aB1);
    }

    // ---- theta (rows 0-7 = regs 0-3 + 4hi), no pooling ----
    {
        h4 tv;
#pragma unroll
        for (int r = 0; r < 4; ++r) tv[r] = (_Float16)aA0[r];
        *(h4*)&theta_t[(size_t)((b << 12) + sA) * 8 + 4 * hi] = tv;
#pragma unroll
        for (int r = 0; r < 4; ++r) tv[r] = (_Float16)aB0[r];
        *(h4*)&theta_t[(size_t)((b << 12) + sA + 64) * 8 + 4 * hi] = tv;
    }

    // ---- pooled phi / g ----
    int t = rp * 32 + wt * 16 + (ln >> 1);
    float pv[4];
#pragma unroll
    for (int j = 0; j < 4; ++j) {
        float m = fmaxf(aA0[4 + j], aB0[4 + j]);
        m = fmaxf(m, __shfl_xor(m, 1));
        pv[j] = m;
    }
    float gv[4][4];
#pragma unroll
    for (int j = 0; j < 4; ++j) {
        float m0 = fmaxf(aA0[8 + j],  aB0[8 + j]);
        float m1 = fmaxf(aA0[12 + j], aB0[12 + j]);
        float m2 = fmaxf(aA1[j],      aB1[j]);
        float m3 = fmaxf(aA1[4 + j],  aB1[4 + j]);
        gv[0][j] = fmaxf(m0, __shfl_xor(m0, 1));
        gv[1][j] = fmaxf(m1, __shfl_xor(m1, 1));
        gv[2][j] = fmaxf(m2, __shfl_xor(m2, 1));
        gv[3][j] = fmaxf(m3, __shfl_xor(m3, 1));
    }
    if ((l & 1) == 0) {
        h4 pj;
#pragma unroll
        for (int j = 0; j < 4; ++j) pj[j] = (_Float16)pv[j];
        *(h4*)&phi_t[(size_t)((b << 10) + t) * 8 + 4 * hi] = pj;
        // blocked g: [b][t>>2][c][t&3]
        _Float16* gb = g_blk + ((size_t)(b * 256 + (t >> 2)) * 32) * 4 + (t & 3);
#pragma unroll
        for (int part = 0; part < 4; ++part) {
            int cbase = part * 8 + 4 * hi;
#pragma unroll
            for (int j = 0; j < 4; ++j)
                gb[(size_t)(cbase + j) * 4] = (_Float16)gv[part][j];
        }
    }
}

// ---------------------------------------------------------------------------
// KA: flash attention, swapped-operand 32x32x8 MFMA, P in registers.
// Two-pass exact softmax: pass 1 computes per-row (per-lane) max via 32
// score MFMAs + in-register fmax trees; pass 2 folds -m into the score
// MFMA's C-init, p = exp2(sc) in (0,1]. No clamp, no online rescale.
// g A-fragments load directly from L2 (blocked layout, 512B-coalesced),
// prefetched one chunk ahead. ZERO LDS, ZERO barriers.
// ---------------------------------------------------------------------------
__global__ __launch_bounds__(256) void k_attn(
        const float* __restrict__ x, const _Float16* __restrict__ theta_t,
        const _Float16* __restrict__ phi_t, const _Float16* __restrict__ g_blk,
        const float* __restrict__ w_o, const float* __restrict__ gamma_p,
        float* __restrict__ out) {
    int tid = threadIdx.x;
    int bid = blockIdx.x;
    int wg = (bid & 7) * 64 + (bid >> 3);    // XCD-contiguous batches (512%8==0)
    int b = wg >> 5;
    int s0 = (wg & 31) * 128;
    int l = tid & 63;
    int ln = l & 31, hi = l >> 5;
    int sw = s0 + (tid >> 6) * 32;

    // theta B-fragment (col s = sw+ln, k = o = 4*hi+i), loop-invariant
    h4 bth = *(const h4*)&theta_t[(size_t)((b << 12) + sw + ln) * 8 + 4 * hi];

    // w_o A-fragments: ch = mt*32+ln, k = c = 8*kk + 4*hi + i
    h4 a3[2][4];
#pragma unroll
    for (int mt = 0; mt < 2; ++mt)
#pragma unroll
        for (int kk = 0; kk < 4; ++kk) {
            float4 wv = *(const float4*)&w_o[(mt * 32 + ln) * CG + 8 * kk + 4 * hi];
            a3[mt][kk][0] = (_Float16)wv.x;
            a3[mt][kk][1] = (_Float16)wv.y;
            a3[mt][kk][2] = (_Float16)wv.z;
            a3[mt][kk][3] = (_Float16)wv.w;
        }

    const _Float16* phib = phi_t + ((size_t)b << 10) * 8;
    const _Float16* gbb  = g_blk + (size_t)b * (256 * 128);

    f32x16 zero;
#pragma unroll
    for (int r = 0; r < 16; ++r) zero[r] = 0.f;

    // ---- pass 1: exact per-lane row max over all 1024 keys ----
    float mx = -1e30f;
#pragma unroll 8
    for (int tc = 0; tc < TT / 32; ++tc) {
        h4 ap = *(const h4*)&phib[(size_t)(tc * 32 + ln) * 8 + 4 * hi];
        f32x16 sc = MFMA328(ap, bth, zero);
        float y0 = fmaxf(sc[0], sc[1]),   y1 = fmaxf(sc[2], sc[3]);
        float y2 = fmaxf(sc[4], sc[5]),   y3 = fmaxf(sc[6], sc[7]);
        float y4 = fmaxf(sc[8], sc[9]),   y5 = fmaxf(sc[10], sc[11]);
        float y6 = fmaxf(sc[12], sc[13]), y7 = fmaxf(sc[14], sc[15]);
        y0 = fmaxf(y0, y1); y2 = fmaxf(y2, y3);
        y4 = fmaxf(y4, y5); y6 = fmaxf(y6, y7);
        y0 = fmaxf(y0, y2); y4 = fmaxf(y4, y6);
        mx = fmaxf(mx, fmaxf(y0, y4));
    }
    mx = fmaxf(mx, __shfl_xor(mx, 32));

    f32x16 cneg;
#pragma unroll
    for (int r = 0; r < 16; ++r) cneg[r] = -mx;

    f32x16 acc = zero;
    float lsum = 0.f;

    // prefetch chunk 0
    h4 aphi = *(const h4*)&phib[(size_t)ln * 8 + 4 * hi];
    h4 ag[4];
#pragma unroll
    for (int kk = 0; kk < 4; ++kk)
        ag[kk] = *(const h4*)&gbb[(size_t)((2 * kk + hi) * 32 + ln) * 4];

    // ---- pass 2: P = exp2(score - m), PV accumulate ----
#pragma unroll 4
    for (int tc = 0; tc < TT / 32; ++tc) {
        int tn = (tc + 1) & 31;              // wraps; last-iter loads unused
        h4 aphi_n = *(const h4*)&phib[(size_t)(tn * 32 + ln) * 8 + 4 * hi];
        h4 agn[4];
#pragma unroll
        for (int kk = 0; kk < 4; ++kk)
            agn[kk] = *(const h4*)&gbb[(size_t)((tn * 8 + 2 * kk + hi) * 32 + ln) * 4];

        // scores D[t][s] - m (shift folded into C-init)
        f32x16 sc = MFMA328(aphi, bth, cneg);

        // p = exp2(sc); accumulate lsum; pack B-fragments
        h4 bp[4];
        float pa = 0.f, pb2 = 0.f;
#pragma unroll
        for (int kk = 0; kk < 4; ++kk)
#pragma unroll
            for (int i = 0; i < 4; ++i) {
                float p = EXP2(sc[4 * kk + i]);
                if (kk < 2) pa += p; else pb2 += p;
                bp[kk][i] = (_Float16)p;
            }
        lsum += pa + pb2;

        // PV: acc[c][s] += g[c][t] * P[t][s]
#pragma unroll
        for (int kk = 0; kk < 4; ++kk) acc = MFMA328(ag[kk], bp[kk], acc);

        aphi = aphi_n;
#pragma unroll
        for (int kk = 0; kk < 4; ++kk) ag[kk] = agn[kk];
    }

    // lane's s column is split across hi halves: combine sums
    lsum += __shfl_xor(lsum, 32);
    float linv = 1.f / lsum;

    // ---- epilogue: out = gamma * (w_o . attn/l) + x, attn regs -> B-frags ----
    h4 bat[4];
#pragma unroll
    for (int kk = 0; kk < 4; ++kk) {
        bat[kk][0] = (_Float16)(acc[4 * kk + 0] * linv);
        bat[kk][1] = (_Float16)(acc[4 * kk + 1] * linv);
        bat[kk][2] = (_Float16)(acc[4 * kk + 2] * linv);
        bat[kk][3] = (_Float16)(acc[4 * kk + 3] * linv);
    }
    float gm = gamma_p[0];
#pragma unroll
    for (int mt = 0; mt < 2; ++mt) {
        f32x16 d = MFMA328(a3[mt][0], bat[0], zero);
        d = MFMA328(a3[mt][1], bat[1], d);
        d = MFMA328(a3[mt][2], bat[2], d);
        d = MFMA328(a3[mt][3], bat[3], d);
#pragma unroll
        for (int r = 0; r < 16; ++r) {
            int ch = mt * 32 + (r & 3) + 8 * (r >> 2) + 4 * hi;
            size_t idx = (((size_t)(b * C + ch)) << 12) + sw + ln;
            out[idx] = gm * d[r] + x[idx];
        }
    }
}

// ---------------------------------------------------------------------------
extern "C" void kernel_launch(void* const* d_in, const int* in_sizes, int n_in,
                              void* d_out, int out_size, void* d_ws, size_t ws_size,
                              hipStream_t stream) {
    const float* x       = (const float*)d_in[0];
    const float* w_theta = (const float*)d_in[1];
    const float* w_phi   = (const float*)d_in[2];
    const float* w_g     = (const float*)d_in[3];
    const float* w_o     = (const float*)d_in[4];
    const float* gamma   = (const float*)d_in[5];
    float* out = (float*)d_out;

    _Float16* ws      = (_Float16*)d_ws;
    _Float16* theta_t = ws;                             // B*SS*8  halves
    _Float16* phi_t   = theta_t + (size_t)B * SS * 8;   // B*TT*8
    _Float16* g_blk   = phi_t + (size_t)B * TT * 8;     // B*TT*CG (blocked)

    k_proj<<<256, 256, 0, stream>>>(x, w_theta, w_phi, w_g, theta_t, phi_t, g_blk);
    k_attn<<<B * (SS / 128), 256, 0, stream>>>(x, theta_t, phi_t, g_blk,
                                               w_o, gamma, out);
}

// Round 9
// 35.619 us; speedup vs baseline: 2.4859x; 1.2469x over previous
//
#include <hip/hip_runtime.h>

#define B 16
#define C 64
#define SS 4096      // H*W
#define TT 1024      // pooled keys
#define CQ 8         // C/8
#define CG 32        // C/2

typedef _Float16 h4 __attribute__((ext_vector_type(4)));
typedef float f32x16 __attribute__((ext_vector_type(16)));

#if __has_builtin(__builtin_amdgcn_exp2f)
#define EXP2(x) __builtin_amdgcn_exp2f(x)
#else
#define EXP2(x) exp2f(x)
#endif

#define MFMA328(a, b, c) __builtin_amdgcn_mfma_f32_32x32x8f16((a), (b), (c), 0, 0, 0)

// ---------------------------------------------------------------------------
// KP: projections via MFMA, zero LDS, zero barriers (unchanged from R6).
// Outputs: theta_t[b][s][o] f16 (o-contig, pre-scaled log2e), phi_t[b][t][o],
//          g_blk[b][t>>2][c][t&3] f16 (blocked: KA frag loads are 512B-coalesced)
// ---------------------------------------------------------------------------
__global__ __launch_bounds__(256) void k_proj(
        const float* __restrict__ x, const float* __restrict__ w_theta,
        const float* __restrict__ w_phi, const float* __restrict__ w_g,
        _Float16* __restrict__ theta_t, _Float16* __restrict__ phi_t,
        _Float16* __restrict__ g_blk) {
    int tid = threadIdx.x;
    int W = blockIdx.x * 4 + (tid >> 6);     // 1024 wave-tasks
    int l = tid & 63;
    int ln = l & 31, hi = l >> 5;
    int b = W >> 6, ws = W & 63;
    int rp = ws >> 1, wt = ws & 1;           // row-pair 0..31, w-tile 0..1
    int sA = rp * 128 + wt * 32 + ln;        // pixel (2rp, 32wt+ln)

    // ---- A-fragments (weights), loaded once ----
    const float LOG2E = 1.44269504088896f;
    float wsc = 1.f;
    const float* wr0;
    if (ln < 8)       { wr0 = w_theta + ln * C; wsc = LOG2E; }
    else if (ln < 16) { wr0 = w_phi + (ln - 8) * C; }
    else              { wr0 = w_g + (ln - 16) * C; }
    const float* wr1 = w_g + (16 + (ln & 15)) * C;  // used only when ln<16
    bool t1v = ln < 16;

    h4 wa0[8], wa1[8];
#pragma unroll
    for (int kk = 0; kk < 8; ++kk) {
        float4 v0 = *(const float4*)&wr0[8 * kk + 4 * hi];
        float4 v1 = *(const float4*)&wr1[8 * kk + 4 * hi];
        wa0[kk][0] = (_Float16)(v0.x * wsc);
        wa0[kk][1] = (_Float16)(v0.y * wsc);
        wa0[kk][2] = (_Float16)(v0.z * wsc);
        wa0[kk][3] = (_Float16)(v0.w * wsc);
        wa1[kk][0] = t1v ? (_Float16)v1.x : (_Float16)0.f;
        wa1[kk][1] = t1v ? (_Float16)v1.y : (_Float16)0.f;
        wa1[kk][2] = t1v ? (_Float16)v1.z : (_Float16)0.f;
        wa1[kk][3] = t1v ? (_Float16)v1.w : (_Float16)0.f;
    }

    // ---- x loads: 64 independent coalesced scalar f32 per lane ----
    const float* xb = x + ((size_t)b << 18);
    float xA[8][4], xB[8][4];
#pragma unroll
    for (int kk = 0; kk < 8; ++kk)
#pragma unroll
        for (int i = 0; i < 4; ++i) {
            int c = 8 * kk + 4 * hi + i;
            xA[kk][i] = xb[((size_t)c << 12) + sA];
            xB[kk][i] = xb[((size_t)c << 12) + sA + 64];
        }

    f32x16 aA0, aA1, aB0, aB1;
#pragma unroll
    for (int r = 0; r < 16; ++r) { aA0[r] = 0.f; aA1[r] = 0.f; aB0[r] = 0.f; aB1[r] = 0.f; }

#pragma unroll
    for (int kk = 0; kk < 8; ++kk) {
        h4 bA, bB;
#pragma unroll
        for (int i = 0; i < 4; ++i) {
            bA[i] = (_Float16)xA[kk][i];
            bB[i] = (_Float16)xB[kk][i];
        }
        aA0 = MFMA328(wa0[kk], bA, aA0);
        aB0 = MFMA328(wa0[kk], bB, aB0);
        aA1 = MFMA328(wa1[kk], bA, aA1);
        aB1 = MFMA328(wa1[kk], bB, aB1);
    }

    // ---- theta (rows 0-7 = regs 0-3 + 4hi), no pooling ----
    {
        h4 tv;
#pragma unroll
        for (int r = 0; r < 4; ++r) tv[r] = (_Float16)aA0[r];
        *(h4*)&theta_t[(size_t)((b << 12) + sA) * 8 + 4 * hi] = tv;
#pragma unroll
        for (int r = 0; r < 4; ++r) tv[r] = (_Float16)aB0[r];
        *(h4*)&theta_t[(size_t)((b << 12) + sA + 64) * 8 + 4 * hi] = tv;
    }

    // ---- pooled phi / g ----
    int t = rp * 32 + wt * 16 + (ln >> 1);
    float pv[4];
#pragma unroll
    for (int j = 0; j < 4; ++j) {
        float m = fmaxf(aA0[4 + j], aB0[4 + j]);
        m = fmaxf(m, __shfl_xor(m, 1));
        pv[j] = m;
    }
    float gv[4][4];
#pragma unroll
    for (int j = 0; j < 4; ++j) {
        float m0 = fmaxf(aA0[8 + j],  aB0[8 + j]);
        float m1 = fmaxf(aA0[12 + j], aB0[12 + j]);
        float m2 = fmaxf(aA1[j],      aB1[j]);
        float m3 = fmaxf(aA1[4 + j],  aB1[4 + j]);
        gv[0][j] = fmaxf(m0, __shfl_xor(m0, 1));
        gv[1][j] = fmaxf(m1, __shfl_xor(m1, 1));
        gv[2][j] = fmaxf(m2, __shfl_xor(m2, 1));
        gv[3][j] = fmaxf(m3, __shfl_xor(m3, 1));
    }
    if ((l & 1) == 0) {
        h4 pj;
#pragma unroll
        for (int j = 0; j < 4; ++j) pj[j] = (_Float16)pv[j];
        *(h4*)&phi_t[(size_t)((b << 10) + t) * 8 + 4 * hi] = pj;
        // blocked g: [b][t>>2][c][t&3]
        _Float16* gb = g_blk + ((size_t)(b * 256 + (t >> 2)) * 32) * 4 + (t & 3);
#pragma unroll
        for (int part = 0; part < 4; ++part) {
            int cbase = part * 8 + 4 * hi;
#pragma unroll
            for (int j = 0; j < 4; ++j)
                gb[(size_t)(cbase + j) * 4] = (_Float16)gv[part][j];
        }
    }
}

// ---------------------------------------------------------------------------
// KA: flash attention, swapped-operand 32x32x8 MFMA, P in registers.
// Two-pass exact softmax. ILP restructure: even/odd chunks form independent
// dataflow chains (split accumulators accA/accB, lsumA/lsumB), prefetch
// depth 2 via explicit 2-stage register rotation. ZERO LDS, ZERO barriers.
// ---------------------------------------------------------------------------
__global__ __launch_bounds__(256) void k_attn(
        const float* __restrict__ x, const _Float16* __restrict__ theta_t,
        const _Float16* __restrict__ phi_t, const _Float16* __restrict__ g_blk,
        const float* __restrict__ w_o, const float* __restrict__ gamma_p,
        float* __restrict__ out) {
    int tid = threadIdx.x;
    int bid = blockIdx.x;
    int wg = (bid & 7) * 64 + (bid >> 3);    // XCD-contiguous batches (512%8==0)
    int b = wg >> 5;
    int s0 = (wg & 31) * 128;
    int l = tid & 63;
    int ln = l & 31, hi = l >> 5;
    int sw = s0 + (tid >> 6) * 32;

    // theta B-fragment (col s = sw+ln, k = o = 4*hi+i), loop-invariant
    h4 bth = *(const h4*)&theta_t[(size_t)((b << 12) + sw + ln) * 8 + 4 * hi];

    // w_o A-fragments: ch = mt*32+ln, k = c = 8*kk + 4*hi + i
    h4 a3[2][4];
#pragma unroll
    for (int mt = 0; mt < 2; ++mt)
#pragma unroll
        for (int kk = 0; kk < 4; ++kk) {
            float4 wv = *(const float4*)&w_o[(mt * 32 + ln) * CG + 8 * kk + 4 * hi];
            a3[mt][kk][0] = (_Float16)wv.x;
            a3[mt][kk][1] = (_Float16)wv.y;
            a3[mt][kk][2] = (_Float16)wv.z;
            a3[mt][kk][3] = (_Float16)wv.w;
        }

    const _Float16* phib = phi_t + ((size_t)b << 10) * 8;
    const _Float16* gbb  = g_blk + (size_t)b * (256 * 128);

    f32x16 zero;
#pragma unroll
    for (int r = 0; r < 16; ++r) zero[r] = 0.f;

#define LD_PHI(t_) (*(const h4*)&phib[(size_t)((t_) * 32 + ln) * 8 + 4 * hi])
#define LD_G(dst, t_)                                                          \
    {                                                                          \
        _Pragma("unroll")                                                      \
        for (int kk = 0; kk < 4; ++kk)                                         \
            dst[kk] = *(const h4*)&gbb[(size_t)(((t_) * 8 + 2 * kk + hi) * 32 + ln) * 4]; \
    }
#define FMAX16(dst, sc_)                                                       \
    {                                                                          \
        float y0 = fmaxf(sc_[0], sc_[1]),   y1 = fmaxf(sc_[2], sc_[3]);        \
        float y2 = fmaxf(sc_[4], sc_[5]),   y3 = fmaxf(sc_[6], sc_[7]);        \
        float y4 = fmaxf(sc_[8], sc_[9]),   y5 = fmaxf(sc_[10], sc_[11]);      \
        float y6 = fmaxf(sc_[12], sc_[13]), y7 = fmaxf(sc_[14], sc_[15]);      \
        y0 = fmaxf(y0, y1); y2 = fmaxf(y2, y3);                                \
        y4 = fmaxf(y4, y5); y6 = fmaxf(y6, y7);                                \
        y0 = fmaxf(y0, y2); y4 = fmaxf(y4, y6);                                \
        dst = fmaxf(dst, fmaxf(y0, y4));                                       \
    }

    // ---- pass 1: exact per-lane row max; even/odd interleave, prefetch 2 ----
    float mx0 = -1e30f, mx1 = -1e30f;
    h4 p1a = LD_PHI(0);
    h4 p1b = LD_PHI(1);
#pragma unroll 4
    for (int tc = 0; tc < TT / 32; tc += 2) {
        h4 p1an = LD_PHI((tc + 2) & 31);
        h4 p1bn = LD_PHI((tc + 3) & 31);
        f32x16 s0 = MFMA328(p1a, bth, zero);
        f32x16 s1 = MFMA328(p1b, bth, zero);
        FMAX16(mx0, s0);
        FMAX16(mx1, s1);
        p1a = p1an;
        p1b = p1bn;
    }
    float mx = fmaxf(mx0, mx1);
    mx = fmaxf(mx, __shfl_xor(mx, 32));

    f32x16 cneg;
#pragma unroll
    for (int r = 0; r < 16; ++r) cneg[r] = -mx;

    // ---- pass 2: P = exp2(score - m), PV accumulate; independent even/odd
    //      chains (accA/accB), prefetch depth 2 ----
    f32x16 accA = zero, accB = zero;
    float lsumA = 0.f, lsumB = 0.f;

    h4 apA = LD_PHI(0);
    h4 apB = LD_PHI(1);
    h4 agA[4], agB[4];
    LD_G(agA, 0);
    LD_G(agB, 1);

#pragma unroll 2
    for (int tc = 0; tc < TT / 32; tc += 2) {
        int t2 = (tc + 2) & 31, t3 = (tc + 3) & 31;
        h4 apAn = LD_PHI(t2);
        h4 apBn = LD_PHI(t3);
        h4 agAn[4], agBn[4];
        LD_G(agAn, t2);
        LD_G(agBn, t3);

        // even chunk
        f32x16 scA = MFMA328(apA, bth, cneg);
        // odd chunk (independent — compiler interleaves under even's chain)
        f32x16 scB = MFMA328(apB, bth, cneg);

        h4 bpA[4], bpB[4];
        float pa0 = 0.f, pa1 = 0.f, pb0 = 0.f, pb1 = 0.f;
#pragma unroll
        for (int kk = 0; kk < 4; ++kk)
#pragma unroll
            for (int i = 0; i < 4; ++i) {
                float pA = EXP2(scA[4 * kk + i]);
                float pB = EXP2(scB[4 * kk + i]);
                if (kk < 2) { pa0 += pA; pb0 += pB; }
                else        { pa1 += pA; pb1 += pB; }
                bpA[kk][i] = (_Float16)pA;
                bpB[kk][i] = (_Float16)pB;
            }
        lsumA += pa0 + pa1;
        lsumB += pb0 + pb1;

#pragma unroll
        for (int kk = 0; kk < 4; ++kk) accA = MFMA328(agA[kk], bpA[kk], accA);
#pragma unroll
        for (int kk = 0; kk < 4; ++kk) accB = MFMA328(agB[kk], bpB[kk], accB);

        apA = apAn;
        apB = apBn;
#pragma unroll
        for (int kk = 0; kk < 4; ++kk) { agA[kk] = agAn[kk]; agB[kk] = agBn[kk]; }
    }

    f32x16 acc = accA + accB;
    float lsum = lsumA + lsumB;
    lsum += __shfl_xor(lsum, 32);
    float linv = 1.f / lsum;

    // ---- epilogue: out = gamma * (w_o . attn/l) + x, attn regs -> B-frags ----
    h4 bat[4];
#pragma unroll
    for (int kk = 0; kk < 4; ++kk) {
        bat[kk][0] = (_Float16)(acc[4 * kk + 0] * linv);
        bat[kk][1] = (_Float16)(acc[4 * kk + 1] * linv);
        bat[kk][2] = (_Float16)(acc[4 * kk + 2] * linv);
        bat[kk][3] = (_Float16)(acc[4 * kk + 3] * linv);
    }
    float gm = gamma_p[0];
#pragma unroll
    for (int mt = 0; mt < 2; ++mt) {
        f32x16 d = MFMA328(a3[mt][0], bat[0], zero);
        d = MFMA328(a3[mt][1], bat[1], d);
        d = MFMA328(a3[mt][2], bat[2], d);
        d = MFMA328(a3[mt][3], bat[3], d);
#pragma unroll
        for (int r = 0; r < 16; ++r) {
            int ch = mt * 32 + (r & 3) + 8 * (r >> 2) + 4 * hi;
            size_t idx = (((size_t)(b * C + ch)) << 12) + sw + ln;
            out[idx] = gm * d[r] + x[idx];
        }
    }
#undef LD_PHI
#undef LD_G
#undef FMAX16
}

// ---------------------------------------------------------------------------
extern "C" void kernel_launch(void* const* d_in, const int* in_sizes, int n_in,
                              void* d_out, int out_size, void* d_ws, size_t ws_size,
                              hipStream_t stream) {
    const float* x       = (const float*)d_in[0];
    const float* w_theta = (const float*)d_in[1];
    const float* w_phi   = (const float*)d_in[2];
    const float* w_g     = (const float*)d_in[3];
    const float* w_o     = (const float*)d_in[4];
    const float* gamma   = (const float*)d_in[5];
    float* out = (float*)d_out;

    _Float16* ws      = (_Float16*)d_ws;
    _Float16* theta_t = ws;                             // B*SS*8  halves
    _Float16* phi_t   = theta_t + (size_t)B * SS * 8;   // B*TT*8
    _Float16* g_blk   = phi_t + (size_t)B * TT * 8;     // B*TT*CG (blocked)

    k_proj<<<256, 256, 0, stream>>>(x, w_theta, w_phi, w_g, theta_t, phi_t, g_blk);
    k_attn<<<B * (SS / 128), 256, 0, stream>>>(x, theta_t, phi_t, g_blk,
                                               w_o, gamma, out);
}

// Round 11
// 32.909 us; speedup vs baseline: 2.6906x; 1.0823x over previous
//
#include <hip/hip_runtime.h>

#define B 16
#define C 64
#define SS 4096      // H*W
#define TT 1024      // pooled keys
#define CQ 8         // C/8
#define CG 32        // C/2

typedef _Float16 h4 __attribute__((ext_vector_type(4)));
typedef float f32x16 __attribute__((ext_vector_type(16)));

#if __has_builtin(__builtin_amdgcn_exp2f)
#define EXP2(x) __builtin_amdgcn_exp2f(x)
#else
#define EXP2(x) exp2f(x)
#endif

#define MFMA328(a, b, c) __builtin_amdgcn_mfma_f32_32x32x8f16((a), (b), (c), 0, 0, 0)

// ---------------------------------------------------------------------------
// KP: projections via MFMA, zero LDS, zero barriers (R6/R9 version, no norms).
// Outputs: theta_t[b][s][o] f16 (o-contig, pre-scaled log2e), phi_t[b][t][o],
//          g_blk[b][t>>2][c][t&3] f16 (blocked: KA frag loads 512B-coalesced)
// ---------------------------------------------------------------------------
__global__ __launch_bounds__(256) void k_proj(
        const float* __restrict__ x, const float* __restrict__ w_theta,
        const float* __restrict__ w_phi, const float* __restrict__ w_g,
        _Float16* __restrict__ theta_t, _Float16* __restrict__ phi_t,
        _Float16* __restrict__ g_blk) {
    int tid = threadIdx.x;
    int W = blockIdx.x * 4 + (tid >> 6);     // 1024 wave-tasks
    int l = tid & 63;
    int ln = l & 31, hi = l >> 5;
    int b = W >> 6, ws = W & 63;
    int rp = ws >> 1, wt = ws & 1;           // row-pair 0..31, w-tile 0..1
    int sA = rp * 128 + wt * 32 + ln;        // pixel (2rp, 32wt+ln)

    // ---- A-fragments (weights), loaded once ----
    const float LOG2E = 1.44269504088896f;
    float wsc = 1.f;
    const float* wr0;
    if (ln < 8)       { wr0 = w_theta + ln * C; wsc = LOG2E; }
    else if (ln < 16) { wr0 = w_phi + (ln - 8) * C; }
    else              { wr0 = w_g + (ln - 16) * C; }
    const float* wr1 = w_g + (16 + (ln & 15)) * C;  // used only when ln<16
    bool t1v = ln < 16;

    h4 wa0[8], wa1[8];
#pragma unroll
    for (int kk = 0; kk < 8; ++kk) {
        float4 v0 = *(const float4*)&wr0[8 * kk + 4 * hi];
        float4 v1 = *(const float4*)&wr1[8 * kk + 4 * hi];
        wa0[kk][0] = (_Float16)(v0.x * wsc);
        wa0[kk][1] = (_Float16)(v0.y * wsc);
        wa0[kk][2] = (_Float16)(v0.z * wsc);
        wa0[kk][3] = (_Float16)(v0.w * wsc);
        wa1[kk][0] = t1v ? (_Float16)v1.x : (_Float16)0.f;
        wa1[kk][1] = t1v ? (_Float16)v1.y : (_Float16)0.f;
        wa1[kk][2] = t1v ? (_Float16)v1.z : (_Float16)0.f;
        wa1[kk][3] = t1v ? (_Float16)v1.w : (_Float16)0.f;
    }

    // ---- x loads: 64 independent coalesced scalar f32 per lane ----
    const float* xb = x + ((size_t)b << 18);
    float xA[8][4], xB[8][4];
#pragma unroll
    for (int kk = 0; kk < 8; ++kk)
#pragma unroll
        for (int i = 0; i < 4; ++i) {
            int c = 8 * kk + 4 * hi + i;
            xA[kk][i] = xb[((size_t)c << 12) + sA];
            xB[kk][i] = xb[((size_t)c << 12) + sA + 64];
        }

    f32x16 aA0, aA1, aB0, aB1;
#pragma unroll
    for (int r = 0; r < 16; ++r) { aA0[r] = 0.f; aA1[r] = 0.f; aB0[r] = 0.f; aB1[r] = 0.f; }

#pragma unroll
    for (int kk = 0; kk < 8; ++kk) {
        h4 bA, bB;
#pragma unroll
        for (int i = 0; i < 4; ++i) {
            bA[i] = (_Float16)xA[kk][i];
            bB[i] = (_Float16)xB[kk][i];
        }
        aA0 = MFMA328(wa0[kk], bA, aA0);
        aB0 = MFMA328(wa0[kk], bB, aB0);
        aA1 = MFMA328(wa1[kk], bA, aA1);
        aB1 = MFMA328(wa1[kk], bB, aB1);
    }

    // ---- theta (rows 0-7 = regs 0-3 + 4hi), no pooling ----
    {
        h4 tv;
#pragma unroll
        for (int r = 0; r < 4; ++r) tv[r] = (_Float16)aA0[r];
        *(h4*)&theta_t[(size_t)((b << 12) + sA) * 8 + 4 * hi] = tv;
#pragma unroll
        for (int r = 0; r < 4; ++r) tv[r] = (_Float16)aB0[r];
        *(h4*)&theta_t[(size_t)((b << 12) + sA + 64) * 8 + 4 * hi] = tv;
    }

    // ---- pooled phi / g ----
    int t = rp * 32 + wt * 16 + (ln >> 1);
    float pv[4];
#pragma unroll
    for (int j = 0; j < 4; ++j) {
        float m = fmaxf(aA0[4 + j], aB0[4 + j]);
        m = fmaxf(m, __shfl_xor(m, 1));
        pv[j] = m;
    }
    float gv[4][4];
#pragma unroll
    for (int j = 0; j < 4; ++j) {
        float m0 = fmaxf(aA0[8 + j],  aB0[8 + j]);
        float m1 = fmaxf(aA0[12 + j], aB0[12 + j]);
        float m2 = fmaxf(aA1[j],      aB1[j]);
        float m3 = fmaxf(aA1[4 + j],  aB1[4 + j]);
        gv[0][j] = fmaxf(m0, __shfl_xor(m0, 1));
        gv[1][j] = fmaxf(m1, __shfl_xor(m1, 1));
        gv[2][j] = fmaxf(m2, __shfl_xor(m2, 1));
        gv[3][j] = fmaxf(m3, __shfl_xor(m3, 1));
    }
    if ((l & 1) == 0) {
        h4 pj;
#pragma unroll
        for (int j = 0; j < 4; ++j) pj[j] = (_Float16)pv[j];
        *(h4*)&phi_t[(size_t)((b << 10) + t) * 8 + 4 * hi] = pj;
        // blocked g: [b][t>>2][c][t&3]
        _Float16* gb = g_blk + ((size_t)(b * 256 + (t >> 2)) * 32) * 4 + (t & 3);
#pragma unroll
        for (int part = 0; part < 4; ++part) {
            int cbase = part * 8 + 4 * hi;
#pragma unroll
            for (int j = 0; j < 4; ++j)
                gb[(size_t)(cbase + j) * 4] = (_Float16)gv[part][j];
        }
    }
}

// ---------------------------------------------------------------------------
// KA: split-K flash attention. 512 blocks x 8 waves; wave pair (w, w+4)
// shares 32 query rows, each half handles 512 keys (16 chunks) with exact
// two-pass softmax. Flash-combine through LDS (one barrier); epilogue split
// by channel-half. 4 waves/SIMD occupancy (launch_bounds caps VGPR at 128).
// ---------------------------------------------------------------------------
__global__ __launch_bounds__(512, 4) void k_attn(
        const float* __restrict__ x, const _Float16* __restrict__ theta_t,
        const _Float16* __restrict__ phi_t, const _Float16* __restrict__ g_blk,
        const float* __restrict__ w_o, const float* __restrict__ gamma_p,
        float* __restrict__ out) {
    __shared__ float accx[8][16][64];   // 32 KB: per-wave acc fragments
    __shared__ float mlx[8][2][64];     // 4 KB: per-wave (m, lsum)

    int tid = threadIdx.x;
    int bid = blockIdx.x;
    int wg = (bid & 7) * 64 + (bid >> 3);    // XCD-contiguous (512 = 8*64)
    int b = wg >> 5;
    int s0 = (wg & 31) * 128;
    int w = tid >> 6;
    int l = tid & 63;
    int ln = l & 31, hi = l >> 5;
    int sub = w & 3, half = w >> 2;
    int sw = s0 + sub * 32;
    int h16 = half * 16;                     // this half's chunk base

    // theta B-fragment (col s = sw+ln, k = o = 4*hi+i), loop-invariant
    h4 bth = *(const h4*)&theta_t[(size_t)((b << 12) + sw + ln) * 8 + 4 * hi];

    const _Float16* phib = phi_t + ((size_t)b << 10) * 8;
    const _Float16* gbb  = g_blk + (size_t)b * (256 * 128);

    f32x16 zero;
#pragma unroll
    for (int r = 0; r < 16; ++r) zero[r] = 0.f;

#define LD_PHI(t_) (*(const h4*)&phib[(size_t)((t_) * 32 + ln) * 8 + 4 * hi])
#define LD_G(dst, t_)                                                          \
    {                                                                          \
        _Pragma("unroll")                                                      \
        for (int kk = 0; kk < 4; ++kk)                                         \
            dst[kk] = *(const h4*)&gbb[(size_t)(((t_) * 8 + 2 * kk + hi) * 32 + ln) * 4]; \
    }
#define FMAX16(dst, sc_)                                                       \
    {                                                                          \
        float y0 = fmaxf(sc_[0], sc_[1]),   y1 = fmaxf(sc_[2], sc_[3]);        \
        float y2 = fmaxf(sc_[4], sc_[5]),   y3 = fmaxf(sc_[6], sc_[7]);        \
        float y4 = fmaxf(sc_[8], sc_[9]),   y5 = fmaxf(sc_[10], sc_[11]);      \
        float y6 = fmaxf(sc_[12], sc_[13]), y7 = fmaxf(sc_[14], sc_[15]);      \
        y0 = fmaxf(y0, y1); y2 = fmaxf(y2, y3);                                \
        y4 = fmaxf(y4, y5); y6 = fmaxf(y6, y7);                                \
        y0 = fmaxf(y0, y2); y4 = fmaxf(y4, y6);                                \
        dst = fmaxf(dst, fmaxf(y0, y4));                                       \
    }

    // ---- pass 1: exact row max over this half's 512 keys ----
    float mx = -1e30f;
    {
        h4 pa = LD_PHI(h16);
        h4 pb = LD_PHI(h16 + 1);
#pragma unroll 2
        for (int tc = 0; tc < 16; tc += 2) {
            h4 pan = LD_PHI(h16 + ((tc + 2) & 15));
            h4 pbn = LD_PHI(h16 + ((tc + 3) & 15));
            f32x16 sa = MFMA328(pa, bth, zero);
            f32x16 sb = MFMA328(pb, bth, zero);
            FMAX16(mx, sa);
            FMAX16(mx, sb);
            pa = pan;
            pb = pbn;
        }
        mx = fmaxf(mx, __shfl_xor(mx, 32));
    }

    f32x16 cneg;
#pragma unroll
    for (int r = 0; r < 16; ++r) cneg[r] = -mx;

    // ---- pass 2: P = exp2(score - m), PV accumulate (depth-2 prefetch) ----
    f32x16 acc = zero;
    float lsum = 0.f;
    h4 ap = LD_PHI(h16);
    h4 ap2 = LD_PHI(h16 + 1);
    h4 ag[4], ag2[4];
    LD_G(ag, h16);
    LD_G(ag2, h16 + 1);

#pragma unroll 2
    for (int tc = 0; tc < 16; ++tc) {
        int tn = h16 + ((tc + 2) & 15);
        h4 apn = LD_PHI(tn);
        h4 agn[4];
        LD_G(agn, tn);

        f32x16 sc = MFMA328(ap, bth, cneg);

        h4 bp[4];
        float pa0 = 0.f, pa1 = 0.f;
#pragma unroll
        for (int kk = 0; kk < 4; ++kk)
#pragma unroll
            for (int i = 0; i < 4; ++i) {
                float p = EXP2(sc[4 * kk + i]);
                if (kk < 2) pa0 += p; else pa1 += p;
                bp[kk][i] = (_Float16)p;
            }
        lsum += pa0 + pa1;

#pragma unroll
        for (int kk = 0; kk < 4; ++kk) acc = MFMA328(ag[kk], bp[kk], acc);

        ap = ap2; ap2 = apn;
#pragma unroll
        for (int kk = 0; kk < 4; ++kk) { ag[kk] = ag2[kk]; ag2[kk] = agn[kk]; }
    }
    lsum += __shfl_xor(lsum, 32);

    // ---- exchange partials through LDS ----
#pragma unroll
    for (int r = 0; r < 16; ++r) accx[w][r][l] = acc[r];
    mlx[w][0][l] = mx;
    mlx[w][1][l] = lsum;
    __syncthreads();

    int p = w ^ 4;
    float m2 = mlx[p][0][l], l2 = mlx[p][1][l];
    float M = fmaxf(mx, m2);
    float f1 = EXP2(mx - M), f2 = EXP2(m2 - M);
    float lt = lsum * f1 + l2 * f2;
    float linv = 1.f / lt;

    h4 bat[4];
#pragma unroll
    for (int kk = 0; kk < 4; ++kk)
#pragma unroll
        for (int i = 0; i < 4; ++i) {
            float a2 = accx[p][4 * kk + i][l];
            bat[kk][i] = (_Float16)((acc[4 * kk + i] * f1 + a2 * f2) * linv);
        }

    // ---- epilogue: this half does channels [half*32, half*32+32) ----
    float gm = gamma_p[0];
    h4 a3[4];
#pragma unroll
    for (int kk = 0; kk < 4; ++kk) {
        float4 wv = *(const float4*)&w_o[(half * 32 + ln) * CG + 8 * kk + 4 * hi];
        a3[kk][0] = (_Float16)(wv.x * gm);
        a3[kk][1] = (_Float16)(wv.y * gm);
        a3[kk][2] = (_Float16)(wv.z * gm);
        a3[kk][3] = (_Float16)(wv.w * gm);
    }
    f32x16 d = MFMA328(a3[0], bat[0], zero);
    d = MFMA328(a3[1], bat[1], d);
    d = MFMA328(a3[2], bat[2], d);
    d = MFMA328(a3[3], bat[3], d);
#pragma unroll
    for (int r = 0; r < 16; ++r) {
        int ch = half * 32 + (r & 3) + 8 * (r >> 2) + 4 * hi;
        size_t idx = (((size_t)(b * C + ch)) << 12) + sw + ln;
        out[idx] = d[r] + x[idx];
    }
#undef LD_PHI
#undef LD_G
#undef FMAX16
}

// ---------------------------------------------------------------------------
extern "C" void kernel_launch(void* const* d_in, const int* in_sizes, int n_in,
                              void* d_out, int out_size, void* d_ws, size_t ws_size,
                              hipStream_t stream) {
    const float* x       = (const float*)d_in[0];
    const float* w_theta = (const float*)d_in[1];
    const float* w_phi   = (const float*)d_in[2];
    const float* w_g     = (const float*)d_in[3];
    const float* w_o     = (const float*)d_in[4];
    const float* gamma   = (const float*)d_in[5];
    float* out = (float*)d_out;

    _Float16* ws      = (_Float16*)d_ws;
    _Float16* theta_t = ws;                             // B*SS*8  halves (1 MB)
    _Float16* phi_t   = theta_t + (size_t)B * SS * 8;   // B*TT*8  (256 KB)
    _Float16* g_blk   = phi_t + (size_t)B * TT * 8;     // B*TT*CG (1 MB)

    k_proj<<<256, 256, 0, stream>>>(x, w_theta, w_phi, w_g, theta_t, phi_t, g_blk);
    k_attn<<<512, 512, 0, stream>>>(x, theta_t, phi_t, g_blk, w_o, gamma, out);
}